// Round 1
// 536.884 us; speedup vs baseline: 1.0297x; 1.0297x over previous
//
#include <hip/hip_runtime.h>
#include <hip/hip_bf16.h>

typedef __bf16 bf16;
typedef __bf16 bf16x4 __attribute__((ext_vector_type(4)));
typedef __bf16 bf16x8 __attribute__((ext_vector_type(8)));
typedef float  f32x4  __attribute__((ext_vector_type(4)));

#define DEVFN static __device__ __forceinline__

static constexpr int T_STEPS = 25;
static constexpr int BATCH   = 256;
static constexpr int MROWS   = T_STEPS * BATCH;  // 6400

// async global->LDS, 16B/lane; LDS base must be wave-uniform (HW adds lane*16).
DEVFN void llds16(const void* g, void* l) {
    __builtin_amdgcn_global_load_lds(
        (const __attribute__((address_space(1))) void*)g,
        (__attribute__((address_space(3))) void*)l, 16, 0, 0);
}

// ---------------------------------------------------------------------------
// Precision splits (unchanged, R1/R3/R4/R8-verified): G0/G1 weights and x need
// 3 bf16 planes; w2 needs 2. Spike margins ~1e-7 make all kept passes required.
DEVFN void split3_chunk(const float* src, bf16* p0, bf16* p1, bf16* p2, int i) {
    float4 v = *(const float4*)(src + i);
    float vv[4] = {v.x, v.y, v.z, v.w};
    bf16x4 a, b, c;
#pragma unroll
    for (int k = 0; k < 4; ++k) {
        bf16 h0 = (bf16)vv[k];
        float r1 = vv[k] - (float)h0;      // exact
        bf16 h1 = (bf16)r1;
        float r2 = r1 - (float)h1;         // exact
        a[k] = h0; b[k] = h1; c[k] = (bf16)r2;
    }
    *(bf16x4*)(p0 + i) = a;
    *(bf16x4*)(p1 + i) = b;
    *(bf16x4*)(p2 + i) = c;
}

DEVFN void split2_chunk(const float* src, bf16* p0, bf16* p1, int i) {
    float4 v = *(const float4*)(src + i);
    float vv[4] = {v.x, v.y, v.z, v.w};
    bf16x4 a, b;
#pragma unroll
    for (int k = 0; k < 4; ++k) {
        bf16 h0 = (bf16)vv[k];
        a[k] = h0; b[k] = (bf16)(vv[k] - (float)h0);
    }
    *(bf16x4*)(p0 + i) = a;
    *(bf16x4*)(p1 + i) = b;
}

static constexpr int SB_W0 = 2048;
static constexpr int SB_W1 = 4096;
static constexpr int SB_W2 = 2048;
static constexpr int SB_X  = 6400;

__global__ void split_all(const float* __restrict__ w0, bf16* w0p0, bf16* w0p1, bf16* w0p2,
                          const float* __restrict__ w1, bf16* w1p0, bf16* w1p1, bf16* w1p2,
                          const float* __restrict__ w2, bf16* w2p0, bf16* w2p1,
                          const float* __restrict__ x,  bf16* xp0,  bf16* xp1,  bf16* xp2) {
    int b = blockIdx.x;
    if (b < SB_W0) {
        split3_chunk(w0, w0p0, w0p1, w0p2, b * 1024 + threadIdx.x * 4);
    } else if (b < SB_W0 + SB_W1) {
        split3_chunk(w1, w1p0, w1p1, w1p2, (b - SB_W0) * 1024 + threadIdx.x * 4);
    } else if (b < SB_W0 + SB_W1 + SB_W2) {
        split2_chunk(w2, w2p0, w2p1, (b - SB_W0 - SB_W1) * 1024 + threadIdx.x * 4);
    } else {
        split3_chunk(x, xp0, xp1, xp2, (b - SB_W0 - SB_W1 - SB_W2) * 1024 + threadIdx.x * 4);
    }
}

// ---------------------------------------------------------------------------
// Phased multi-plane GEMM (this round's change).
// Geometry: BM=256, BN=128, BK=32, 512 threads = 8 waves (4M x 2N), each wave
// owns a 64x64 sub-tile = 4x4 MFMA tiles of 16x16x32 bf16 -> the frag4 /
// mfma16 / epilogue machinery and the R6-verified XOR swizzle carry over
// unchanged (SQ_LDS_BANK_CONFLICT==0).
// Schedule: T3+T4+T5 from the catalog. One 16-MFMA phase per precision pass;
// staging for K-tile t+1 is spread across tile t's phases; per-phase counted
// vmcnt(N) where N = #loads issued AFTER the newest load the NEXT phase's
// ds_reads need (never 0 in main loop); raw s_barrier (no vmcnt(0) drain);
// s_setprio(1) around each MFMA cluster.
// Correctness of gating: a region is ds_read only after [vmcnt(N) covering its
// loads; s_barrier] executed by ALL waves (vmcnt is per-wave, barrier makes it
// collective). Write-after-read at tile boundary is protected by each phase's
// trailing barrier (all waves passed lgkmcnt(0) before anyone stages over the
// old buffer).

template <int N> DEVFN void vmw() {
    asm volatile("s_waitcnt vmcnt(%0)" :: "n"(N) : "memory");
}
DEVFN void lgkm0() {
    asm volatile("s_waitcnt lgkmcnt(0)" ::: "memory");
    __builtin_amdgcn_sched_barrier(0);   // rule #18: pin MFMA after the wait
}
DEVFN void bar() {
    asm volatile("" ::: "memory");
    __builtin_amdgcn_s_barrier();
    asm volatile("" ::: "memory");
}

struct TileCtx { int t, lane, wm, wn, bm, bn, fr, fkS, cr, cc; };

DEVFN TileCtx make_ctx512() {
    TileCtx x;
    x.t = threadIdx.x; x.lane = x.t & 63;
    int wv = x.t >> 6;                       // 0..7
    x.wm = (wv >> 1) * 64;                   // 0,64,128,192 within BM=256
    x.wn = (wv & 1) * 64;                    // 0,64       within BN=128
    x.bm = blockIdx.x * 256; x.bn = blockIdx.y * 128;
    x.fr  = x.lane & 15;
    x.fkS = (((x.lane >> 4) ^ ((x.lane >> 1) & 3))) * 16;   // swizzled chunk, bytes
    x.cr = (x.lane >> 4) * 4; x.cc = x.lane & 15;
    return x;
}

// stage a ROWSx32 bf16 plane into LDS, swizzled: LDS slot (r,q) holds global
// chunk q ^ ((r>>1)&3); dest is lane-linear (global_load_lds requirement),
// source address carries the swizzle (rule #21: both-sides-or-neither).
template <int ROWS>
DEVFN void stage(const bf16* g, bf16* s, int base_row, int K, int k0, int t) {
#pragma unroll
    for (int r = 0; r < ROWS / 128; ++r) {
        int c   = t + r * 512;               // 16B chunk index
        int row = c >> 2;
        int kc  = (((c & 3) ^ ((c >> 3) & 3))) * 8;
        llds16(g + (size_t)(base_row + row) * K + k0 + kc,
               (bf16*)((char*)s + (c >> 6) * 1024));
    }
}

// swizzled LDS fragment read (A and B operands); row stride 64B
DEVFN void frag4(bf16x8* f, const bf16* s, int wrow, int fr, int fkS) {
#pragma unroll
    for (int i = 0; i < 4; ++i)
        f[i] = *(const bf16x8*)((const char*)s + (wrow + i * 16 + fr) * 64 + fkS);
}

DEVFN void mfma16(f32x4 (&acc)[4][4], const bf16x8* a, const bf16x8* b) {
#pragma unroll
    for (int i = 0; i < 4; ++i)
#pragma unroll
        for (int j = 0; j < 4; ++j)
            acc[i][j] = __builtin_amdgcn_mfma_f32_16x16x32_bf16(a[i], b[j], acc[i][j], 0, 0, 0);
}

// fp64 merge: accM + accS + bias summed in double, single round to f32.
DEVFN void epilogue(const f32x4 (&accM)[4][4], const f32x4 (&accS)[4][4],
                    const float* bias, float* C, int N, const TileCtx& x) {
#pragma unroll
    for (int j = 0; j < 4; ++j) {
        int col   = x.bn + x.wn + j * 16 + x.cc;
        double bv = (double)bias[col];
#pragma unroll
        for (int i = 0; i < 4; ++i) {
            int row0 = x.bm + x.wm + i * 16 + x.cr;
#pragma unroll
            for (int r = 0; r < 4; ++r) {
                double v = (double)accM[i][j][r] + (double)accS[i][j][r] + bv;
                C[(size_t)(row0 + r) * N + col] = (float)v;
            }
        }
    }
}

// MODE 0: L0  (3 A planes, 3 B planes, 6 phases/K-tile, 9 loads/thread/tile)
// MODE 1: L1  (1 A plane,  3 B planes, 3 phases,        5 loads)
// MODE 2: L2  (1 A plane,  2 B planes, 2 phases,        4 loads)
template <int MODE>
__global__ __launch_bounds__(512, 2)
void gemm_ph(const bf16* __restrict__ A0, const bf16* __restrict__ A1,
             const bf16* __restrict__ A2, const bf16* __restrict__ B0,
             const bf16* __restrict__ B1, const bf16* __restrict__ B2,
             const float* __restrict__ bias, float* __restrict__ C,
             int M, int N, int K) {
    constexpr int NA  = (MODE == 0) ? 3 : 1;
    constexpr int NB  = (MODE == 2) ? 2 : 3;
    constexpr int APL = 256 * 32;            // A plane elems (16 KiB)
    constexpr int BPL = 128 * 32;            // B plane elems ( 8 KiB)
    constexpr int BUF = NA * APL + NB * BPL;
    __shared__ __align__(1024) bf16 lds[2 * BUF];   // MODE0:144K  1:80K  2:64K

    TileCtx x = make_ctx512();
    f32x4 accM[4][4] = {}, accS[4][4] = {};

    auto pA = [&](int p, int i) { return lds + p * BUF + i * APL; };
    auto pB = [&](int p, int i) { return lds + p * BUF + NA * APL + i * BPL; };

    // prologue: tile 0 fully into buf 0, one-time full drain
    if constexpr (MODE == 0) {
        stage<256>(A0, pA(0, 0), x.bm, K, 0, x.t);
        stage<256>(A1, pA(0, 1), x.bm, K, 0, x.t);
        stage<256>(A2, pA(0, 2), x.bm, K, 0, x.t);
    } else {
        stage<256>(A0, pA(0, 0), x.bm, K, 0, x.t);
    }
    stage<128>(B0, pB(0, 0), x.bn, K, 0, x.t);
    stage<128>(B1, pB(0, 1), x.bn, K, 0, x.t);
    if constexpr (NB == 3) stage<128>(B2, pB(0, 2), x.bn, K, 0, x.t);
    vmw<0>(); bar();

    const int NT = K / 32;
    int p = 0;
    for (int tt = 0; tt < NT; ++tt, p ^= 1) {
        const int  kn = (tt + 1) * 32;
        const bool pf = (tt + 1 < NT);
        bf16x8 a[4], b0f[4], b1f[4], b2f[4];

        if constexpr (MODE == 0) {
            // issue plan for tile t+1: P0:A0(2) P1:B0(1) P2:B1+B2(2) P3:A1(2) P4:A2(2)
            // P0: accM += a0*b0   (reads gated by prev-tile P5 vmcnt(6)+bar)
            frag4(a,   pA(p, 0), x.wm, x.fr, x.fkS);
            frag4(b0f, pB(p, 0), x.wn, x.fr, x.fkS);
            if (pf) stage<256>(A0, pA(p ^ 1, 0), x.bm, K, kn, x.t);
            vmw<7>(); bar(); lgkm0();          // covers P1's b1 (prev P2 #1; 7 younger)
            __builtin_amdgcn_s_setprio(1); mfma16(accM, a, b0f); __builtin_amdgcn_s_setprio(0);
            bar();
            // P1: accS += a0*b1
            frag4(b1f, pB(p, 1), x.wn, x.fr, x.fkS);
            if (pf) stage<128>(B0, pB(p ^ 1, 0), x.bn, K, kn, x.t);
            vmw<7>(); bar(); lgkm0();          // covers P2's b2 (prev P2 #2)
            __builtin_amdgcn_s_setprio(1); mfma16(accS, a, b1f); __builtin_amdgcn_s_setprio(0);
            bar();
            // P2: accS += a0*b2
            frag4(b2f, pB(p, 2), x.wn, x.fr, x.fkS);
            if (pf) { stage<128>(B1, pB(p ^ 1, 1), x.bn, K, kn, x.t);
                      stage<128>(B2, pB(p ^ 1, 2), x.bn, K, kn, x.t); }
            vmw<7>(); bar(); lgkm0();          // covers P3's a1 (prev P3 pair)
            __builtin_amdgcn_s_setprio(1); mfma16(accS, a, b2f); __builtin_amdgcn_s_setprio(0);
            bar();
            // P3: accS += a1*b0  (b0f persists)
            frag4(a, pA(p, 1), x.wm, x.fr, x.fkS);
            if (pf) stage<256>(A1, pA(p ^ 1, 1), x.bm, K, kn, x.t);
            bar(); lgkm0();                    // P4 has no ds reads -> no vmcnt
            __builtin_amdgcn_s_setprio(1); mfma16(accS, a, b0f); __builtin_amdgcn_s_setprio(0);
            bar();
            // P4: accS += a1*b1  (no ds reads)
            if (pf) stage<256>(A2, pA(p ^ 1, 2), x.bm, K, kn, x.t);
            vmw<9>(); bar(); lgkm0();          // covers P5's a2 (prev P4 pair; 9 younger)
            __builtin_amdgcn_s_setprio(1); mfma16(accS, a, b1f); __builtin_amdgcn_s_setprio(0);
            bar();
            // P5: accS += a2*b0
            frag4(a, pA(p, 2), x.wm, x.fr, x.fkS);
            vmw<6>(); bar(); lgkm0();          // covers next-tile P0 a0,b0 (this P0/P1)
            __builtin_amdgcn_s_setprio(1); mfma16(accS, a, b0f); __builtin_amdgcn_s_setprio(0);
            bar();
        } else if constexpr (MODE == 1) {
            // issue plan: P0:A(2) P1:B0(1) P2:B1+B2(2)
            // P0: accM += a*b0
            frag4(a,   pA(p, 0), x.wm, x.fr, x.fkS);
            frag4(b0f, pB(p, 0), x.wn, x.fr, x.fkS);
            if (pf) stage<256>(A0, pA(p ^ 1, 0), x.bm, K, kn, x.t);
            vmw<3>(); bar(); lgkm0();          // covers P1's b1 (prev P2 #1; 3 younger)
            __builtin_amdgcn_s_setprio(1); mfma16(accM, a, b0f); __builtin_amdgcn_s_setprio(0);
            bar();
            // P1: accS += a*b1
            frag4(b1f, pB(p, 1), x.wn, x.fr, x.fkS);
            if (pf) stage<128>(B0, pB(p ^ 1, 0), x.bn, K, kn, x.t);
            vmw<3>(); bar(); lgkm0();          // covers P2's b2 (prev P2 #2)
            __builtin_amdgcn_s_setprio(1); mfma16(accS, a, b1f); __builtin_amdgcn_s_setprio(0);
            bar();
            // P2: accS += a*b2
            frag4(b2f, pB(p, 2), x.wn, x.fr, x.fkS);
            if (pf) { stage<128>(B1, pB(p ^ 1, 1), x.bn, K, kn, x.t);
                      stage<128>(B2, pB(p ^ 1, 2), x.bn, K, kn, x.t); }
            vmw<2>(); bar(); lgkm0();          // covers next-tile P0 a,b0 (this P0/P1)
            __builtin_amdgcn_s_setprio(1); mfma16(accS, a, b2f); __builtin_amdgcn_s_setprio(0);
            bar();
        } else {
            // issue plan: P0: A(2)+B0(1)+B1(1)
            // P0: accM += a*b0
            frag4(a,   pA(p, 0), x.wm, x.fr, x.fkS);
            frag4(b0f, pB(p, 0), x.wn, x.fr, x.fkS);
            if (pf) { stage<256>(A0, pA(p ^ 1, 0), x.bm, K, kn, x.t);
                      stage<128>(B0, pB(p ^ 1, 0), x.bn, K, kn, x.t);
                      stage<128>(B1, pB(p ^ 1, 1), x.bn, K, kn, x.t); }
            vmw<4>(); bar(); lgkm0();          // covers P1's b1 (prev P0 #4; 4 younger)
            __builtin_amdgcn_s_setprio(1); mfma16(accM, a, b0f); __builtin_amdgcn_s_setprio(0);
            bar();
            // P1: accS += a*b1
            frag4(b1f, pB(p, 1), x.wn, x.fr, x.fkS);
            vmw<1>(); bar(); lgkm0();          // covers next-tile P0 a,b0 (this P0 #1-3)
            __builtin_amdgcn_s_setprio(1); mfma16(accS, a, b1f); __builtin_amdgcn_s_setprio(0);
            bar();
        }
    }
    epilogue(accM, accS, bias, C, N, x);
}

// ---------------------------------------------------------------------------
// LIF scans — fp64 recurrence (R4-verified: kills the f32 drift flips).
template <int F>
__global__ void lif_hidden(const float* __restrict__ cur, bf16* __restrict__ spk) {
    const int tid = blockIdx.x * 256 + threadIdx.x;  // b*F + f
    double m = 0.0;
    size_t off = tid;
#pragma unroll
    for (int t = 0; t < T_STEPS; ++t) {
        m = 0.9 * m + (double)cur[off];
        bool s = (m - 1.0) > 0.0;
        spk[off] = (bf16)(s ? 1.0f : 0.0f);
        if (s) m -= 1.0;
        off += (size_t)BATCH * F;
    }
}

__global__ void lif_out(const float* __restrict__ cur, float* __restrict__ out) {
    const int tid = blockIdx.x * 256 + threadIdx.x;  // b*1024 + f
    double m = 0.0;
    size_t off = tid;
#pragma unroll
    for (int t = 0; t < T_STEPS; ++t) {
        m = 0.9 * m + (double)cur[off];
        bool s = (m - 1.0) > 0.0;
        out[off] = s ? 1.0f : 0.0f;
        if (s) m -= 1.0;
        off += (size_t)BATCH * 1024;
    }
    out[(size_t)T_STEPS * BATCH * 1024 + tid] = (float)m;  // final membrane (output 1)
}

// ---------------------------------------------------------------------------
extern "C" void kernel_launch(void* const* d_in, const int* in_sizes, int n_in,
                              void* d_out, int out_size, void* d_ws, size_t ws_size,
                              hipStream_t stream) {
    const float* xin = (const float*)d_in[0];
    const float* w0  = (const float*)d_in[1];
    const float* b0  = (const float*)d_in[2];
    const float* w1  = (const float*)d_in[3];
    const float* b1  = (const float*)d_in[4];
    const float* w2  = (const float*)d_in[5];
    const float* b2  = (const float*)d_in[6];
    float* out = (float*)d_out;

    constexpr size_t NW0 = 2048 * 1024;
    constexpr size_t NW1 = 2048 * 2048;
    constexpr size_t NW2 = 1024 * 2048;
    constexpr size_t NX  = (size_t)MROWS * 1024;  // 6,553,600
    constexpr size_t NH  = (size_t)MROWS * 2048;  // 13,107,200

    char* ws = (char*)d_ws;
    size_t off = 0;
    auto carve = [&](size_t bytes) { char* p = ws + off; off += bytes; return p; };

    // long-lived planes
    bf16* w1p0 = (bf16*)carve(NW1 * 2);
    bf16* w1p1 = (bf16*)carve(NW1 * 2);
    bf16* w1p2 = (bf16*)carve(NW1 * 2);
    bf16* w2p0 = (bf16*)carve(NW2 * 2);
    bf16* w2p1 = (bf16*)carve(NW2 * 2);
    // pool: w0 planes + x planes live only until G0; s0/s1 overlay afterwards
    char* pool = carve(2 * NH * 2);          // 52,428,800 B
    bf16* w0p0 = (bf16*)pool;
    bf16* w0p1 = w0p0 + NW0;
    bf16* w0p2 = w0p1 + NW0;
    bf16* xp0  = w0p2 + NW0;
    bf16* xp1  = xp0 + NX;
    bf16* xp2  = xp1 + NX;                   // ends at pool + 51,904,512
    bf16* s0   = (bf16*)pool;                // written after G0 consumed w0/x
    bf16* s1   = s0 + NH;                    // written after G1 consumed s0
    float* cur = (float*)carve(NH * 4);
    if (ws_size < off) return;               // 138,412,032 B total

    // 1) fused precision splits (one launch)
    split_all<<<SB_W0 + SB_W1 + SB_W2 + SB_X, 256, 0, stream>>>(
        w0, w0p0, w0p1, w0p2, w1, w1p0, w1p1, w1p2,
        w2, w2p0, w2p1, xin, xp0, xp1, xp2);

    // 2) layer 0: cur0 = x @ W0^T + b0 (M=6400,N=2048,K=1024; 6-pass dual-acc)
    gemm_ph<0><<<dim3(25, 16), 512, 0, stream>>>(xp0, xp1, xp2, w0p0, w0p1, w0p2,
                                                 b0, cur, MROWS, 2048, 1024);
    lif_hidden<2048><<<(BATCH * 2048) / 256, 256, 0, stream>>>(cur, s0);

    // 3) layer 1: cur1 = s0 @ W1^T + b1 (K=2048; 3-pass dual-acc)
    gemm_ph<1><<<dim3(25, 16), 512, 0, stream>>>(s0, nullptr, nullptr, w1p0, w1p1, w1p2,
                                                 b1, cur, MROWS, 2048, 2048);
    lif_hidden<2048><<<(BATCH * 2048) / 256, 256, 0, stream>>>(cur, s1);

    // 4) layer 2: cur2 = s1 @ W2^T + b2 (N=1024; 2-pass dual-acc)
    gemm_ph<2><<<dim3(25, 8), 512, 0, stream>>>(s1, nullptr, nullptr, w2p0, w2p1, nullptr,
                                                b2, cur, MROWS, 1024, 2048);
    lif_out<<<(BATCH * 1024) / 256, 256, 0, stream>>>(cur, out);
}

// Round 2
// 512.130 us; speedup vs baseline: 1.0795x; 1.0483x over previous
//
#include <hip/hip_runtime.h>
#include <hip/hip_bf16.h>

typedef __bf16 bf16;
typedef __bf16 bf16x4 __attribute__((ext_vector_type(4)));
typedef __bf16 bf16x8 __attribute__((ext_vector_type(8)));
typedef float  f32x4  __attribute__((ext_vector_type(4)));

#define DEVFN static __device__ __forceinline__

static constexpr int T_STEPS = 25;
static constexpr int BATCH   = 256;
static constexpr int MROWS   = T_STEPS * BATCH;  // 6400

// async global->LDS, 16B/lane; LDS base must be wave-uniform (HW adds lane*16).
DEVFN void llds16(const void* g, void* l) {
    __builtin_amdgcn_global_load_lds(
        (const __attribute__((address_space(1))) void*)g,
        (__attribute__((address_space(3))) void*)l, 16, 0, 0);
}

// ---------------------------------------------------------------------------
// Precision splits (unchanged, R1/R3/R4/R8-verified): G0/G1 weights and x need
// 3 bf16 planes; w2 needs 2. Spike margins ~1e-7 make all kept passes required.
DEVFN void split3_chunk(const float* src, bf16* p0, bf16* p1, bf16* p2, int i) {
    float4 v = *(const float4*)(src + i);
    float vv[4] = {v.x, v.y, v.z, v.w};
    bf16x4 a, b, c;
#pragma unroll
    for (int k = 0; k < 4; ++k) {
        bf16 h0 = (bf16)vv[k];
        float r1 = vv[k] - (float)h0;      // exact
        bf16 h1 = (bf16)r1;
        float r2 = r1 - (float)h1;         // exact
        a[k] = h0; b[k] = h1; c[k] = (bf16)r2;
    }
    *(bf16x4*)(p0 + i) = a;
    *(bf16x4*)(p1 + i) = b;
    *(bf16x4*)(p2 + i) = c;
}

DEVFN void split2_chunk(const float* src, bf16* p0, bf16* p1, int i) {
    float4 v = *(const float4*)(src + i);
    float vv[4] = {v.x, v.y, v.z, v.w};
    bf16x4 a, b;
#pragma unroll
    for (int k = 0; k < 4; ++k) {
        bf16 h0 = (bf16)vv[k];
        a[k] = h0; b[k] = (bf16)(vv[k] - (float)h0);
    }
    *(bf16x4*)(p0 + i) = a;
    *(bf16x4*)(p1 + i) = b;
}

static constexpr int SB_W0 = 2048;
static constexpr int SB_W1 = 4096;
static constexpr int SB_W2 = 2048;
static constexpr int SB_X  = 6400;

__global__ void split_all(const float* __restrict__ w0, bf16* w0p0, bf16* w0p1, bf16* w0p2,
                          const float* __restrict__ w1, bf16* w1p0, bf16* w1p1, bf16* w1p2,
                          const float* __restrict__ w2, bf16* w2p0, bf16* w2p1,
                          const float* __restrict__ x,  bf16* xp0,  bf16* xp1,  bf16* xp2) {
    int b = blockIdx.x;
    if (b < SB_W0) {
        split3_chunk(w0, w0p0, w0p1, w0p2, b * 1024 + threadIdx.x * 4);
    } else if (b < SB_W0 + SB_W1) {
        split3_chunk(w1, w1p0, w1p1, w1p2, (b - SB_W0) * 1024 + threadIdx.x * 4);
    } else if (b < SB_W0 + SB_W1 + SB_W2) {
        split2_chunk(w2, w2p0, w2p1, (b - SB_W0 - SB_W1) * 1024 + threadIdx.x * 4);
    } else {
        split3_chunk(x, xp0, xp1, xp2, (b - SB_W0 - SB_W1 - SB_W2) * 1024 + threadIdx.x * 4);
    }
}

// ---------------------------------------------------------------------------
// R2 schedule: single __syncthreads per K-tile, prefetch distance = 1 full
// tile body. Stages for tile t+1 are issued at the TOP of tile t's body into
// the other LDS buffer; the end-of-body __syncthreads drains them after a
// ~1-tile flight (>=2000 cyc >> 900 cyc HBM latency) -> the vmcnt(0) inside
// __syncthreads is effectively free (unlike stage->sync->consume, which
// exposes full latency; that was the old 34% structure). No inline-asm waits:
// ds_reads are compiler loads, so the compiler emits fine-grained lgkmcnt(N)
// and overlaps the ds_read tail with the leading MFMAs (R1's forced
// lgkmcnt(0)+sched_barrier drains prevented exactly that).
// WAR safety: a wave reaches the end-of-body sync only after issuing its
// MFMAs (=> its ds_reads of buf p are complete), so next tile's stages into
// buf p — issued after that same sync — cannot race any reader.

struct TileCtx { int t, lane, wm, wn, bm, bn, fr, fkS, cr, cc; };

DEVFN TileCtx make_ctx512() {
    TileCtx x;
    x.t = threadIdx.x; x.lane = x.t & 63;
    int wv = x.t >> 6;                       // 0..7
    x.wm = (wv >> 1) * 64;                   // 0,64,128,192 within BM=256
    x.wn = (wv & 1) * 64;                    // 0,64       within BN=128
    x.bm = blockIdx.x * 256; x.bn = blockIdx.y * 128;
    x.fr  = x.lane & 15;
    x.fkS = (((x.lane >> 4) ^ ((x.lane >> 1) & 3))) * 16;   // swizzled chunk, bytes
    x.cr = (x.lane >> 4) * 4; x.cc = x.lane & 15;
    return x;
}

// stage a ROWSx32 bf16 plane into LDS, swizzled: LDS slot (r,q) holds global
// chunk q ^ ((r>>1)&3); dest is lane-linear (global_load_lds requirement),
// source address carries the swizzle (rule #21: both-sides-or-neither).
template <int ROWS>
DEVFN void stage(const bf16* g, bf16* s, int base_row, int K, int k0, int t) {
#pragma unroll
    for (int r = 0; r < ROWS / 128; ++r) {
        int c   = t + r * 512;               // 16B chunk index
        int row = c >> 2;
        int kc  = (((c & 3) ^ ((c >> 3) & 3))) * 8;
        llds16(g + (size_t)(base_row + row) * K + k0 + kc,
               (bf16*)((char*)s + (c >> 6) * 1024));
    }
}

// swizzled LDS fragment read (A and B operands); row stride 64B
DEVFN void frag4(bf16x8* f, const bf16* s, int wrow, int fr, int fkS) {
#pragma unroll
    for (int i = 0; i < 4; ++i)
        f[i] = *(const bf16x8*)((const char*)s + (wrow + i * 16 + fr) * 64 + fkS);
}

DEVFN void mfma16(f32x4 (&acc)[4][4], const bf16x8* a, const bf16x8* b) {
    __builtin_amdgcn_s_setprio(1);
#pragma unroll
    for (int i = 0; i < 4; ++i)
#pragma unroll
        for (int j = 0; j < 4; ++j)
            acc[i][j] = __builtin_amdgcn_mfma_f32_16x16x32_bf16(a[i], b[j], acc[i][j], 0, 0, 0);
    __builtin_amdgcn_s_setprio(0);
}

// fp64 merge: accM + accS + bias summed in double, single round to f32.
DEVFN void epilogue(const f32x4 (&accM)[4][4], const f32x4 (&accS)[4][4],
                    const float* bias, float* C, int N, const TileCtx& x) {
#pragma unroll
    for (int j = 0; j < 4; ++j) {
        int col   = x.bn + x.wn + j * 16 + x.cc;
        double bv = (double)bias[col];
#pragma unroll
        for (int i = 0; i < 4; ++i) {
            int row0 = x.bm + x.wm + i * 16 + x.cr;
#pragma unroll
            for (int r = 0; r < 4; ++r) {
                double v = (double)accM[i][j][r] + (double)accS[i][j][r] + bv;
                C[(size_t)(row0 + r) * N + col] = (float)v;
            }
        }
    }
}

// MODE 0: L0 (3 A planes, 3 B planes, 6 passes)
// MODE 1: L1 (1 A plane,  3 B planes, 3 passes)
// MODE 2: L2 (1 A plane,  2 B planes, 2 passes)
template <int MODE>
__global__ __launch_bounds__(512, 2)
void gemm_ph(const bf16* __restrict__ A0, const bf16* __restrict__ A1,
             const bf16* __restrict__ A2, const bf16* __restrict__ B0,
             const bf16* __restrict__ B1, const bf16* __restrict__ B2,
             const float* __restrict__ bias, float* __restrict__ C,
             int M, int N, int K) {
    constexpr int NA  = (MODE == 0) ? 3 : 1;
    constexpr int NB  = (MODE == 2) ? 2 : 3;
    constexpr int APL = 256 * 32;            // A plane elems (16 KiB)
    constexpr int BPL = 128 * 32;            // B plane elems ( 8 KiB)
    constexpr int BUF = NA * APL + NB * BPL;
    __shared__ __align__(1024) bf16 lds[2 * BUF];   // MODE0:144K  1:80K  2:64K

    TileCtx x = make_ctx512();
    f32x4 accM[4][4] = {}, accS[4][4] = {};

    auto pA = [&](int p, int i) { return lds + p * BUF + i * APL; };
    auto pB = [&](int p, int i) { return lds + p * BUF + NA * APL + i * BPL; };

    auto stage_all = [&](int p, int k0) {
        stage<256>(A0, pA(p, 0), x.bm, K, k0, x.t);
        if constexpr (MODE == 0) {
            stage<256>(A1, pA(p, 1), x.bm, K, k0, x.t);
            stage<256>(A2, pA(p, 2), x.bm, K, k0, x.t);
        }
        stage<128>(B0, pB(p, 0), x.bn, K, k0, x.t);
        stage<128>(B1, pB(p, 1), x.bn, K, k0, x.t);
        if constexpr (NB == 3) stage<128>(B2, pB(p, 2), x.bn, K, k0, x.t);
    };

    // prologue: tile 0 into buf 0; the one full-latency drain of the kernel
    stage_all(0, 0);
    __syncthreads();

    const int NT = K / 32;
    int p = 0;
    for (int tt = 0; tt < NT; ++tt, p ^= 1) {
        // prefetch tile t+1 into the other buffer (flight = rest of this body)
        if (tt + 1 < NT) stage_all(p ^ 1, (tt + 1) * 32);

        bf16x8 a[4], b0f[4], b1f[4], b2f[4];
        if constexpr (MODE == 0) {
            frag4(a,   pA(p, 0), x.wm, x.fr, x.fkS);
            frag4(b0f, pB(p, 0), x.wn, x.fr, x.fkS);
            mfma16(accM, a, b0f);
            frag4(b1f, pB(p, 1), x.wn, x.fr, x.fkS);
            mfma16(accS, a, b1f);
            frag4(b2f, pB(p, 2), x.wn, x.fr, x.fkS);
            mfma16(accS, a, b2f);
            frag4(a, pA(p, 1), x.wm, x.fr, x.fkS);   // a1
            mfma16(accS, a, b0f);
            mfma16(accS, a, b1f);
            frag4(a, pA(p, 2), x.wm, x.fr, x.fkS);   // a2
            mfma16(accS, a, b0f);
        } else if constexpr (MODE == 1) {
            frag4(a,   pA(p, 0), x.wm, x.fr, x.fkS);
            frag4(b0f, pB(p, 0), x.wn, x.fr, x.fkS);
            mfma16(accM, a, b0f);
            frag4(b1f, pB(p, 1), x.wn, x.fr, x.fkS);
            mfma16(accS, a, b1f);
            frag4(b2f, pB(p, 2), x.wn, x.fr, x.fkS);
            mfma16(accS, a, b2f);
        } else {
            frag4(a,   pA(p, 0), x.wm, x.fr, x.fkS);
            frag4(b0f, pB(p, 0), x.wn, x.fr, x.fkS);
            mfma16(accM, a, b0f);
            frag4(b1f, pB(p, 1), x.wn, x.fr, x.fkS);
            mfma16(accS, a, b1f);
        }
        // single per-tile barrier: gates buf(p^1) visibility for next tile and
        // protects buf(p) against next tile's stages (readers are done here).
        __syncthreads();
    }
    epilogue(accM, accS, bias, C, N, x);
}

// ---------------------------------------------------------------------------
// LIF scans — fp64 recurrence (R4-verified: kills the f32 drift flips).
template <int F>
__global__ void lif_hidden(const float* __restrict__ cur, bf16* __restrict__ spk) {
    const int tid = blockIdx.x * 256 + threadIdx.x;  // b*F + f
    double m = 0.0;
    size_t off = tid;
#pragma unroll
    for (int t = 0; t < T_STEPS; ++t) {
        m = 0.9 * m + (double)cur[off];
        bool s = (m - 1.0) > 0.0;
        spk[off] = (bf16)(s ? 1.0f : 0.0f);
        if (s) m -= 1.0;
        off += (size_t)BATCH * F;
    }
}

__global__ void lif_out(const float* __restrict__ cur, float* __restrict__ out) {
    const int tid = blockIdx.x * 256 + threadIdx.x;  // b*1024 + f
    double m = 0.0;
    size_t off = tid;
#pragma unroll
    for (int t = 0; t < T_STEPS; ++t) {
        m = 0.9 * m + (double)cur[off];
        bool s = (m - 1.0) > 0.0;
        out[off] = s ? 1.0f : 0.0f;
        if (s) m -= 1.0;
        off += (size_t)BATCH * 1024;
    }
    out[(size_t)T_STEPS * BATCH * 1024 + tid] = (float)m;  // final membrane (output 1)
}

// ---------------------------------------------------------------------------
extern "C" void kernel_launch(void* const* d_in, const int* in_sizes, int n_in,
                              void* d_out, int out_size, void* d_ws, size_t ws_size,
                              hipStream_t stream) {
    const float* xin = (const float*)d_in[0];
    const float* w0  = (const float*)d_in[1];
    const float* b0  = (const float*)d_in[2];
    const float* w1  = (const float*)d_in[3];
    const float* b1  = (const float*)d_in[4];
    const float* w2  = (const float*)d_in[5];
    const float* b2  = (const float*)d_in[6];
    float* out = (float*)d_out;

    constexpr size_t NW0 = 2048 * 1024;
    constexpr size_t NW1 = 2048 * 2048;
    constexpr size_t NW2 = 1024 * 2048;
    constexpr size_t NX  = (size_t)MROWS * 1024;  // 6,553,600
    constexpr size_t NH  = (size_t)MROWS * 2048;  // 13,107,200

    char* ws = (char*)d_ws;
    size_t off = 0;
    auto carve = [&](size_t bytes) { char* p = ws + off; off += bytes; return p; };

    // long-lived planes
    bf16* w1p0 = (bf16*)carve(NW1 * 2);
    bf16* w1p1 = (bf16*)carve(NW1 * 2);
    bf16* w1p2 = (bf16*)carve(NW1 * 2);
    bf16* w2p0 = (bf16*)carve(NW2 * 2);
    bf16* w2p1 = (bf16*)carve(NW2 * 2);
    // pool: w0 planes + x planes live only until G0; s0/s1 overlay afterwards
    char* pool = carve(2 * NH * 2);          // 52,428,800 B
    bf16* w0p0 = (bf16*)pool;
    bf16* w0p1 = w0p0 + NW0;
    bf16* w0p2 = w0p1 + NW0;
    bf16* xp0  = w0p2 + NW0;
    bf16* xp1  = xp0 + NX;
    bf16* xp2  = xp1 + NX;                   // ends at pool + 51,904,512
    bf16* s0   = (bf16*)pool;                // written after G0 consumed w0/x
    bf16* s1   = s0 + NH;                    // written after G1 consumed s0
    float* cur = (float*)carve(NH * 4);
    if (ws_size < off) return;               // 138,412,032 B total

    // 1) fused precision splits (one launch)
    split_all<<<SB_W0 + SB_W1 + SB_W2 + SB_X, 256, 0, stream>>>(
        w0, w0p0, w0p1, w0p2, w1, w1p0, w1p1, w1p2,
        w2, w2p0, w2p1, xin, xp0, xp1, xp2);

    // 2) layer 0: cur0 = x @ W0^T + b0 (M=6400,N=2048,K=1024; 6-pass dual-acc)
    gemm_ph<0><<<dim3(25, 16), 512, 0, stream>>>(xp0, xp1, xp2, w0p0, w0p1, w0p2,
                                                 b0, cur, MROWS, 2048, 1024);
    lif_hidden<2048><<<(BATCH * 2048) / 256, 256, 0, stream>>>(cur, s0);

    // 3) layer 1: cur1 = s0 @ W1^T + b1 (K=2048; 3-pass dual-acc)
    gemm_ph<1><<<dim3(25, 16), 512, 0, stream>>>(s0, nullptr, nullptr, w1p0, w1p1, w1p2,
                                                 b1, cur, MROWS, 2048, 2048);
    lif_hidden<2048><<<(BATCH * 2048) / 256, 256, 0, stream>>>(cur, s1);

    // 4) layer 2: cur2 = s1 @ W2^T + b2 (N=1024; 2-pass dual-acc)
    gemm_ph<2><<<dim3(25, 8), 512, 0, stream>>>(s1, nullptr, nullptr, w2p0, w2p1, nullptr,
                                                b2, cur, MROWS, 1024, 2048);
    lif_out<<<(BATCH * 1024) / 256, 256, 0, stream>>>(cur, out);
}